// Round 28
// baseline (151.270 us; speedup 1.0000x reference)
//
#include <hip/hip_runtime.h>
#include <math.h>

#define ROWS_TOTAL 8192
#define KDIM 1024
#define NPROTO 32
#define RNK 16
#define OUTD 1024
#define TIE_EPS 1.30e-4
#define DELTA 4.0e-5f
#define FLAG_CAP 4096

__device__ __forceinline__ unsigned short f2bf(float v) {
    unsigned int b = __float_as_uint(v);
    return (unsigned short)((b + 0x7FFFu + ((b >> 16) & 1u)) >> 16);
}

// ---------------------------------------------------------------------------
// prep v3 (unchanged): 132 blocks; emits At, Bt16, Pt, p2g, zeroed counts.
// ---------------------------------------------------------------------------
__global__ __launch_bounds__(256) void prep_kernel(
    const float* __restrict__ A, const float* __restrict__ B,
    const float* __restrict__ proto, float* __restrict__ At,
    float* __restrict__ Bt, unsigned short* __restrict__ Bt16,
    float* __restrict__ Pt, double* __restrict__ p2g,
    int* __restrict__ counts, int* __restrict__ flagcnt)
{
    __shared__ float T[16 * 68];
    __shared__ float U[64 * 20];
    __shared__ double red[32][9];
    __shared__ float TP[32][33];
    const int tid = threadIdx.x;

    if (blockIdx.x < 128) {
        const int p = blockIdx.x >> 2;
        const int c0 = (blockIdx.x & 3) * 4;
        const float4* B4 = (const float4*)(B + (size_t)p * RNK * KDIM);
        const float4* A4 = (const float4*)(A + (size_t)p * OUTD * RNK);
        float4* Bt4 = (float4*)(Bt + (size_t)p * KDIM * RNK);
        float4* At4 = (float4*)(At + (size_t)p * RNK * OUTD);
        unsigned short* Bt16p = Bt16 + (size_t)p * KDIM * RNK;
        for (int c = c0; c < c0 + 4; ++c) {
            {
                int r = tid >> 4, kk = tid & 15;
                float4 v = B4[r * 256 + c * 16 + kk];
                *(float4*)&T[r * 68 + kk * 4] = v;
            }
            {
                int o = tid >> 2, rq = tid & 3;
                float4 v = A4[(c * 64 + o) * 4 + rq];
                *(float4*)&U[o * 20 + rq * 4] = v;
            }
            __syncthreads();
            {
                int k = tid >> 2, rq = tid & 3;
                float4 g = make_float4(T[(rq * 4 + 0) * 68 + k], T[(rq * 4 + 1) * 68 + k],
                                       T[(rq * 4 + 2) * 68 + k], T[(rq * 4 + 3) * 68 + k]);
                Bt4[(c * 64 + k) * 4 + rq] = g;
                unsigned int lo = (unsigned int)f2bf(g.x) | ((unsigned int)f2bf(g.y) << 16);
                unsigned int hi = (unsigned int)f2bf(g.z) | ((unsigned int)f2bf(g.w) << 16);
                *(uint2*)(Bt16p + (size_t)(c * 64 + k) * 16 + rq * 4) = make_uint2(lo, hi);
            }
            {
                int r = tid >> 4, ow = tid & 15;
                float4 g = make_float4(U[(ow * 4 + 0) * 20 + r], U[(ow * 4 + 1) * 20 + r],
                                       U[(ow * 4 + 2) * 20 + r], U[(ow * 4 + 3) * 20 + r]);
                At4[r * 256 + c * 16 + ow] = g;
            }
            __syncthreads();
        }
    } else {
        const int qb = blockIdx.x - 128;    // 0..3
        if (qb == 0) {
            if (tid < 64) counts[tid] = 0;
            if (tid == 64) flagcnt[0] = 0;
            {
                const int p = tid >> 3, seg = tid & 7;
                const float* a = proto + (size_t)p * KDIM + seg * 128;
                double s = 0.0;
                for (int k = 0; k < 128; ++k) {
                    double v = (double)a[k];
                    s = fma(v, v, s);
                }
                red[p][seg] = s;
            }
            __syncthreads();
            if (tid < 32) {
                double acc = red[tid][0];
                #pragma unroll
                for (int j = 1; j < 8; ++j) acc += red[tid][j];
                p2g[tid] = acc;
            }
        }
        float4* Pt4 = (float4*)Pt;
        for (int kc = qb * 8; kc < qb * 8 + 8; ++kc) {
            {
                int cc = tid >> 3, kk4 = tid & 7;
                float4 v = *(const float4*)(proto + (size_t)cc * KDIM + kc * 32 + kk4 * 4);
                TP[cc][kk4 * 4 + 0] = v.x; TP[cc][kk4 * 4 + 1] = v.y;
                TP[cc][kk4 * 4 + 2] = v.z; TP[cc][kk4 * 4 + 3] = v.w;
            }
            __syncthreads();
            {
                int kk = tid >> 3, c4 = tid & 7;
                float4 g = make_float4(TP[c4 * 4 + 0][kk], TP[c4 * 4 + 1][kk],
                                       TP[c4 * 4 + 2][kk], TP[c4 * 4 + 3][kk]);
                Pt4[(kc * 32 + kk) * 8 + c4] = g;
            }
            __syncthreads();
        }
    }
}

#define INS(kb, ib) { \
    bool lt1 = (kb) < k1, lt2 = (kb) < k2, lt3 = (kb) < k3, lt4 = (kb) < k4; \
    float nk4 = lt3 ? k3 : (lt4 ? (kb) : k4); int ni4 = lt3 ? i3 : (lt4 ? (ib) : i4); \
    float nk3 = lt2 ? k2 : (lt3 ? (kb) : k3); int ni3 = lt2 ? i2 : (lt3 ? (ib) : i3); \
    float nk2 = lt1 ? k1 : (lt2 ? (kb) : k2); int ni2 = lt1 ? i1 : (lt2 ? (ib) : i2); \
    k4 = nk4; i4 = ni4; k3 = nk3; i3 = ni3; k2 = nk2; i2 = ni2; \
    if (lt1) { k1 = (kb); i1 = (ib); } }

// ---------------------------------------------------------------------------
// Route v5: 4 rows/block (2048 blocks, ~18.6KB LDS -> 8 blocks/CU, 32
// waves/CU). Selection numerics identical to v3/v4 (same per-row FMA
// orders); fused h phase with 32 lanes per (row,slot) pair.
// ---------------------------------------------------------------------------
__global__ __launch_bounds__(256) void route_kernel(
    const float* __restrict__ x, const float* __restrict__ Pt,
    const float* __restrict__ temp, const double* __restrict__ p2g,
    const unsigned short* __restrict__ Bt16,
    float4* __restrict__ route, float* __restrict__ hws,
    int* __restrict__ counts, int* __restrict__ flagcnt,
    int* __restrict__ flaglist)
{
    __shared__ float Xs[4 * KDIM];      // 16 KB
    __shared__ float part[4][4][33];
    __shared__ float x2p[4][4];
    __shared__ int lcnt[64];
    __shared__ int ps[8];

    const int tid = threadIdx.x;
    const int w = tid >> 6, l = tid & 63;
    const int c4 = l & 7, kslot8 = l >> 3;
    const int rowbase = blockIdx.x * 4;

    if (tid < 64) lcnt[tid] = 0;

    const float4* x4 = (const float4*)x;
    float sq[4];
    #pragma unroll
    for (int j = 0; j < 4; ++j) {
        float4 v = x4[(size_t)rowbase * 256 + j * 256 + tid];
        ((float4*)Xs)[j * 256 + tid] = v;
        sq[j] = fmaf(v.x, v.x, fmaf(v.y, v.y, fmaf(v.z, v.z, v.w * v.w)));
    }
    #pragma unroll
    for (int m = 1; m < 64; m <<= 1) {
        #pragma unroll
        for (int j = 0; j < 4; ++j) sq[j] += __shfl_xor(sq[j], m);
    }
    if (l == 0) {
        #pragma unroll
        for (int j = 0; j < 4; ++j) x2p[w][j] = sq[j];
    }
    __syncthreads();

    {
        float acc[4][4];
        #pragma unroll
        for (int j = 0; j < 4; ++j)
            #pragma unroll
            for (int jj = 0; jj < 4; ++jj) acc[j][jj] = 0.f;

        const float4* Pt4 = (const float4*)Pt;
        const int kbase = w * 256;
        #pragma unroll 4
        for (int i = 0; i < 32; ++i) {
            const int k = kbase + i * 8 + kslot8;
            float4 pv = Pt4[k * 8 + c4];
            #pragma unroll
            for (int j = 0; j < 4; ++j) {
                float xv = Xs[j * KDIM + k];
                acc[j][0] = fmaf(xv, pv.x, acc[j][0]);
                acc[j][1] = fmaf(xv, pv.y, acc[j][1]);
                acc[j][2] = fmaf(xv, pv.z, acc[j][2]);
                acc[j][3] = fmaf(xv, pv.w, acc[j][3]);
            }
        }
        #pragma unroll
        for (int m = 8; m < 64; m <<= 1) {
            #pragma unroll
            for (int j = 0; j < 4; ++j) {
                acc[j][0] += __shfl_xor(acc[j][0], m);
                acc[j][1] += __shfl_xor(acc[j][1], m);
                acc[j][2] += __shfl_xor(acc[j][2], m);
                acc[j][3] += __shfl_xor(acc[j][3], m);
            }
        }
        if (kslot8 == 0) {
            #pragma unroll
            for (int j = 0; j < 4; ++j) {
                part[w][j][4 * c4 + 0] = acc[j][0];
                part[w][j][4 * c4 + 1] = acc[j][1];
                part[w][j][4 * c4 + 2] = acc[j][2];
                part[w][j][4 * c4 + 3] = acc[j][3];
            }
        }
    }
    __syncthreads();

    if (tid < 128) {
        const int rowsel = tid >> 5, c = tid & 31;
        float dsum = (part[0][rowsel][c] + part[1][rowsel][c])
                   + (part[2][rowsel][c] + part[3][rowsel][c]);
        float key = (float)(p2g[c] - 2.0 * (double)dsum);
        float x2 = (x2p[0][rowsel] + x2p[1][rowsel])
                 + (x2p[2][rowsel] + x2p[3][rowsel]);

        float k1 = key, k2 = 3.0e38f, k3 = 3.1e38f, k4 = 3.2e38f;
        int i1 = c, i2 = 64, i3 = 65, i4 = 66;
        #pragma unroll
        for (int m = 1; m < 32; m <<= 1) {
            float b1 = __shfl_xor(k1, m), b2 = __shfl_xor(k2, m);
            float b3 = __shfl_xor(k3, m), b4 = __shfl_xor(k4, m);
            int j1 = __shfl_xor(i1, m), j2 = __shfl_xor(i2, m);
            int j3 = __shfl_xor(i3, m), j4 = __shfl_xor(i4, m);
            INS(b1, j1); INS(b2, j2); INS(b3, j3); INS(b4, j4);
        }
        if (c == 0) {
            const int row = rowbase + rowsel;
            const float tf = fmaxf(fabsf(temp[0]), 0.1f);
            bool amb = (k2 - k1 < DELTA) || (k3 - k2 < DELTA)
                    || (fabsf((k3 - k2) - (float)TIE_EPS) < DELTA)
                    || (k4 - k3 < DELTA);
            bool tie = (k3 - k2) < (float)TIE_EPS;
            bool take3 = tie && (i3 < i2);
            float ksel = take3 ? k3 : k2;
            int   isel = take3 ? i3 : i2;
            float d0 = sqrtf(fmaxf(x2 + k1, 0.f));
            float d1 = sqrtf(fmaxf(x2 + ksel, 0.f));
            float e = expf((d0 - d1) / tf);
            float w0 = 1.f / (1.f + e);
            route[row] = make_float4(__int_as_float(i1), __int_as_float(isel),
                                     w0, e * w0);
            ps[2 * rowsel + 0] = i1;
            ps[2 * rowsel + 1] = isel;
            atomicAdd(&lcnt[i1], 1);
            atomicAdd(&lcnt[32 + isel], 1);
            if (amb) {
                int fi = atomicAdd(flagcnt, 1);
                if (fi < FLAG_CAP) flaglist[fi] = row;
            }
        }
    }
    __syncthreads();
    if (tid < 64) atomicAdd(&counts[tid], lcnt[tid]);

    // ---- fused h phase: 32 lanes per (row,slot) pair ----
    {
        const int pair = tid >> 5;           // 0..7 = row*2 + slot
        const int l5 = tid & 31;
        const int kslot = l5 >> 2;           // 0..7
        const int r4 = l5 & 3;
        const int rrow = pair >> 1, slot = pair & 1;
        const unsigned short* Bp = Bt16 + (size_t)ps[pair] * KDIM * RNK + r4 * 4;
        const float* Xr = &Xs[rrow * KDIM];

        float4 acc = {0.f, 0.f, 0.f, 0.f};
        #pragma unroll 8
        for (int i = 0; i < 128; ++i) {
            const int k = i * 8 + kslot;
            float xv = Xr[k];
            uint2 bv = *(const uint2*)(Bp + (size_t)k * 16);
            float b0 = __uint_as_float((bv.x & 0xFFFFu) << 16);
            float b1 = __uint_as_float(bv.x & 0xFFFF0000u);
            float b2 = __uint_as_float((bv.y & 0xFFFFu) << 16);
            float b3 = __uint_as_float(bv.y & 0xFFFF0000u);
            acc.x = fmaf(xv, b0, acc.x);
            acc.y = fmaf(xv, b1, acc.y);
            acc.z = fmaf(xv, b2, acc.z);
            acc.w = fmaf(xv, b3, acc.w);
        }
        // reduce over kslot (lane bits 2..4)
        #pragma unroll
        for (int msk = 4; msk < 32; msk <<= 1) {
            acc.x += __shfl_xor(acc.x, msk);
            acc.y += __shfl_xor(acc.y, msk);
            acc.z += __shfl_xor(acc.z, msk);
            acc.w += __shfl_xor(acc.w, msk);
        }
        if (kslot == 0)
            *(float4*)(hws + (size_t)(slot * ROWS_TOTAL + rowbase + rrow) * 16 + r4 * 4) = acc;
    }
}

// ---------------------------------------------------------------------------
// Refine + scan v2 (unchanged from round 27): exact f64 re-selection; on a
// changed slot proto, recompute that slot's h (bf16-B). Then scan -> segs.
// ---------------------------------------------------------------------------
__global__ __launch_bounds__(256) void refine_scan_kernel(
    const float* __restrict__ x, const float* __restrict__ proto,
    const float* __restrict__ temp, const double* __restrict__ p2g,
    const unsigned short* __restrict__ Bt16,
    float4* __restrict__ route, float* __restrict__ hws,
    int* __restrict__ counts, const int* __restrict__ flagcnt,
    const int* __restrict__ flaglist, int2* __restrict__ segs)
{
    const int tid = threadIdx.x;
    const int w = tid >> 6, l = tid & 63;
    const int c = l & 31, half = l >> 5;
    const int n = min(flagcnt[0], FLAG_CAP);

    for (int f = w; f < n; f += 4) {
        const int row = flaglist[f];
        const float* xr = x + (size_t)row * KDIM;
        double xs = 0.0;
        for (int k = l * 16; k < l * 16 + 16; ++k) {
            double v = (double)xr[k];
            xs = fma(v, v, xs);
        }
        #pragma unroll
        for (int m = 1; m < 64; m <<= 1) xs += __shfl_xor(xs, m);
        const float* pr = proto + (size_t)c * KDIM + half * 512;
        const float* xh = xr + half * 512;
        double d0a = 0.0, d1a = 0.0;
        for (int k = 0; k < 512; k += 2) {
            d0a = fma((double)xh[k], (double)pr[k], d0a);
            d1a = fma((double)xh[k + 1], (double)pr[k + 1], d1a);
        }
        double acc = d0a + d1a;
        acc += __shfl_xor(acc, 32);
        double key = p2g[c] - 2.0 * acc;

        double k1 = key, k2 = 1.0e300, k3 = 1.1e300;
        int i1 = c, i2 = 64, i3 = 65;
        #pragma unroll
        for (int m = 1; m < 32; m <<= 1) {
            double b1 = __shfl_xor(k1, m), b2 = __shfl_xor(k2, m), b3 = __shfl_xor(k3, m);
            int j1 = __shfl_xor(i1, m), j2 = __shfl_xor(i2, m), j3 = __shfl_xor(i3, m);
            bool c1 = (k1 < b1) || (k1 == b1 && i1 < j1);
            double m1 = c1 ? k1 : b1, M1 = c1 ? b1 : k1;
            int mi1 = c1 ? i1 : j1, Mi1 = c1 ? j1 : i1;
            bool c2 = (k2 < b2) || (k2 == b2 && i2 < j2);
            double m2 = c2 ? k2 : b2;
            int mi2 = c2 ? i2 : j2;
            bool c3 = (k3 < b3) || (k3 == b3 && i3 < j3);
            double m3 = c3 ? k3 : b3;
            int mi3 = c3 ? i3 : j3;
            bool c4 = (M1 < m2) || (M1 == m2 && Mi1 < mi2);
            double t2 = c4 ? M1 : m2, T2 = c4 ? m2 : M1;
            int ti2 = c4 ? Mi1 : mi2, Ti2 = c4 ? mi2 : Mi1;
            bool c5 = (T2 < m3) || (T2 == m3 && Ti2 < mi3);
            k1 = m1; i1 = mi1;
            k2 = t2; i2 = ti2;
            k3 = c5 ? T2 : m3; i3 = c5 ? Ti2 : mi3;
        }
        bool tie = (k3 - k2) < TIE_EPS;
        bool take3 = tie && (i3 < i2);
        int isel = take3 ? i3 : i2;
        double ksel = take3 ? k3 : k2;

        float4 old = route[row];
        int oi1 = __float_as_int(old.x), oisel = __float_as_int(old.y);

        if (l == 0) {
            const double tmp = (double)fmaxf(fabsf(temp[0]), 0.1f);
            double dd0 = sqrt(fmax(xs + k1, 0.0));
            double dd1 = sqrt(fmax(xs + ksel, 0.0));
            float e = expf((float)((dd0 - dd1) / tmp));
            float w0 = 1.f / (1.f + e);
            if (oi1 != i1) { atomicAdd(&counts[oi1], -1); atomicAdd(&counts[i1], 1); }
            if (oisel != isel) { atomicAdd(&counts[32 + oisel], -1); atomicAdd(&counts[32 + isel], 1); }
            route[row] = make_float4(__int_as_float(i1), __int_as_float(isel),
                                     w0, e * w0);
        }
        #pragma unroll
        for (int sl = 0; sl < 2; ++sl) {
            int np = sl ? isel : i1;
            int op = sl ? oisel : oi1;
            if (np != op) {
                const int r = l & 15, kq = l >> 4;
                const unsigned short* Bp = Bt16 + (size_t)np * KDIM * RNK + r;
                float hacc = 0.f;
                for (int k = kq * 256; k < kq * 256 + 256; ++k) {
                    unsigned int bu = (unsigned int)Bp[(size_t)k * 16] << 16;
                    hacc = fmaf(xr[k], __uint_as_float(bu), hacc);
                }
                hacc += __shfl_xor(hacc, 16);
                hacc += __shfl_xor(hacc, 32);
                if (kq == 0)
                    hws[(size_t)(sl * ROWS_TOTAL + row) * 16 + r] = hacc;
            }
        }
    }
    __syncthreads();
    if (tid < 64) {
        int v = atomicAdd(&counts[tid], 0);
        int sum = v;
        #pragma unroll
        for (int off = 1; off < 32; off <<= 1) {
            int u = __shfl_up(sum, off, 32);
            if ((tid & 31) >= off) sum += u;
        }
        counts[tid] = sum - v;
        segs[tid] = make_int2(sum - v, sum);
    }
}

__global__ __launch_bounds__(256) void scatter_kernel(
    const float4* __restrict__ route, int* __restrict__ counts,
    int* __restrict__ rowlist0, int* __restrict__ rowlist1)
{
    __shared__ int lcnt[64];
    __shared__ int gbase[64];
    const int tid = threadIdx.x;
    const int i = blockIdx.x * 256 + tid;
    if (tid < 64) lcnt[tid] = 0;
    __syncthreads();
    float4 rt = route[i];
    int p0 = __float_as_int(rt.x);
    int p1 = __float_as_int(rt.y);
    int lp0 = atomicAdd(&lcnt[p0], 1);
    int lp1 = atomicAdd(&lcnt[32 + p1], 1);
    __syncthreads();
    if (tid < 64) gbase[tid] = atomicAdd(&counts[tid], lcnt[tid]);
    __syncthreads();
    rowlist0[gbase[p0] + lp0] = i;
    rowlist1[gbase[32 + p1] + lp1] = i;
}

// ---------------------------------------------------------------------------
// y v4 (unchanged): row-indexed hws gather.
// ---------------------------------------------------------------------------
__global__ __launch_bounds__(256) void y_kernel(
    const float* __restrict__ At, const float* __restrict__ bias,
    const float4* __restrict__ route, const int* __restrict__ rowlist,
    const int2* __restrict__ segs, const float* __restrict__ hws,
    float* __restrict__ out, int slot)
{
    __shared__ float hsm[16][17];
    __shared__ int rows[16];
    __shared__ float wts[16];

    const int tid = threadIdx.x;
    const int f4 = tid;
    const int p = blockIdx.y;
    const int2 sg = segs[slot * 32 + p];
    const float4* Atp = (const float4*)(At + (size_t)p * RNK * OUTD);
    const float4 bb = ((const float4*)(bias + (size_t)p * OUTD))[f4];

    float4 Areg[16];
    #pragma unroll
    for (int r = 0; r < 16; ++r) Areg[r] = Atp[r * 256 + f4];

    for (int c = blockIdx.x; ; c += gridDim.x) {
        const int base = sg.x + c * 16;
        if (base >= sg.y) break;
        const int m = min(16, sg.y - base);

        if (tid < 16) {
            int rr = rowlist[base + min(tid, m - 1)];
            rows[tid] = rr;
            float4 rt = route[rr];
            wts[tid] = slot ? rt.w : rt.z;
        }
        __syncthreads();
        {
            const int e = tid >> 4, r = tid & 15;
            hsm[e][r] = hws[(size_t)(slot * ROWS_TOTAL + rows[e]) * 16 + r];
        }
        __syncthreads();

        for (int e = 0; e < m; ++e) {
            float4 acc = bb;
            #pragma unroll
            for (int r = 0; r < 16; ++r) {
                float hr = hsm[e][r];
                acc.x = fmaf(hr, Areg[r].x, acc.x);
                acc.y = fmaf(hr, Areg[r].y, acc.y);
                acc.z = fmaf(hr, Areg[r].z, acc.z);
                acc.w = fmaf(hr, Areg[r].w, acc.w);
            }
            const float w = wts[e];
            float4 v = make_float4(w * acc.x, w * acc.y, w * acc.z, w * acc.w);
            float4* dst = (float4*)(out + (size_t)rows[e] * OUTD) + f4;
            if (slot) {
                float4 old = *dst;
                v.x += old.x; v.y += old.y; v.z += old.z; v.w += old.w;
            }
            *dst = v;
        }
        __syncthreads();
    }
}

extern "C" void kernel_launch(void* const* d_in, const int* in_sizes, int n_in,
                              void* d_out, int out_size, void* d_ws, size_t ws_size,
                              hipStream_t stream) {
    const float* x     = (const float*)d_in[0];
    const float* proto = (const float*)d_in[1];
    const float* B     = (const float*)d_in[2];
    const float* A     = (const float*)d_in[3];
    const float* bias  = (const float*)d_in[4];
    const float* temp  = (const float*)d_in[5];
    float* out = (float*)d_out;

    char* wsb = (char*)d_ws;
    float4* route = (float4*)wsb;                              // 128 KB
    int* rowlist0 = (int*)(wsb + 131072);                      // 32 KB
    int* rowlist1 = rowlist0 + ROWS_TOTAL;                     // 32 KB
    int* counts   = (int*)(wsb + 196608);                      // 256 B
    int2* segs    = (int2*)(wsb + 196864);                     // 512 B
    double* p2g   = (double*)(wsb + 197376);                   // 256 B
    int* flagcnt  = (int*)(wsb + 197632);                      // 4 B
    int* flaglist = (int*)(wsb + 197760);                      // 16 KB
    float* Pt     = (float*)(wsb + 262144);                    // 128 KB
    float* Bt     = (float*)(wsb + 393216);                    // 2 MB
    float* At     = (float*)(wsb + 393216 + 2097152);          // 2 MB
    float* hws    = (float*)(wsb + 393216 + 2 * 2097152);      // 1 MB
    unsigned short* Bt16 = (unsigned short*)(wsb + 393216 + 3 * 2097152); // 1 MB

    prep_kernel<<<132, 256, 0, stream>>>(A, B, proto, At, Bt, Bt16, Pt, p2g,
                                         counts, flagcnt);
    route_kernel<<<ROWS_TOTAL / 4, 256, 0, stream>>>(x, Pt, temp, p2g, Bt16,
                                                     route, hws, counts,
                                                     flagcnt, flaglist);
    refine_scan_kernel<<<1, 256, 0, stream>>>(x, proto, temp, p2g, Bt16,
                                              route, hws, counts, flagcnt,
                                              flaglist, segs);
    scatter_kernel<<<ROWS_TOTAL / 256, 256, 0, stream>>>(route, counts, rowlist0, rowlist1);
    y_kernel<<<dim3(16, NPROTO), 256, 0, stream>>>(At, bias, route, rowlist0, segs, hws, out, 0);
    y_kernel<<<dim3(16, NPROTO), 256, 0, stream>>>(At, bias, route, rowlist1, segs, hws, out, 1);
}

// Round 29
// 143.226 us; speedup vs baseline: 1.0562x; 1.0562x over previous
//
#include <hip/hip_runtime.h>
#include <math.h>

#define ROWS_TOTAL 8192
#define KDIM 1024
#define NPROTO 32
#define RNK 16
#define OUTD 1024
#define TIE_EPS 1.30e-4
#define DELTA 4.0e-5f
#define FLAG_CAP 4096

__device__ __forceinline__ unsigned short f2bf(float v) {
    unsigned int b = __float_as_uint(v);
    return (unsigned short)((b + 0x7FFFu + ((b >> 16) & 1u)) >> 16);
}

// ---------------------------------------------------------------------------
// prep v3: 132 blocks; emits At, Bt16, Pt, p2g, zeroed counts/flagcnt.
// ---------------------------------------------------------------------------
__global__ __launch_bounds__(256) void prep_kernel(
    const float* __restrict__ A, const float* __restrict__ B,
    const float* __restrict__ proto, float* __restrict__ At,
    float* __restrict__ Bt, unsigned short* __restrict__ Bt16,
    float* __restrict__ Pt, double* __restrict__ p2g,
    int* __restrict__ counts, int* __restrict__ flagcnt)
{
    __shared__ float T[16 * 68];
    __shared__ float U[64 * 20];
    __shared__ double red[32][9];
    __shared__ float TP[32][33];
    const int tid = threadIdx.x;

    if (blockIdx.x < 128) {
        const int p = blockIdx.x >> 2;
        const int c0 = (blockIdx.x & 3) * 4;
        const float4* B4 = (const float4*)(B + (size_t)p * RNK * KDIM);
        const float4* A4 = (const float4*)(A + (size_t)p * OUTD * RNK);
        float4* Bt4 = (float4*)(Bt + (size_t)p * KDIM * RNK);
        float4* At4 = (float4*)(At + (size_t)p * RNK * OUTD);
        unsigned short* Bt16p = Bt16 + (size_t)p * KDIM * RNK;
        for (int c = c0; c < c0 + 4; ++c) {
            {
                int r = tid >> 4, kk = tid & 15;
                float4 v = B4[r * 256 + c * 16 + kk];
                *(float4*)&T[r * 68 + kk * 4] = v;
            }
            {
                int o = tid >> 2, rq = tid & 3;
                float4 v = A4[(c * 64 + o) * 4 + rq];
                *(float4*)&U[o * 20 + rq * 4] = v;
            }
            __syncthreads();
            {
                int k = tid >> 2, rq = tid & 3;
                float4 g = make_float4(T[(rq * 4 + 0) * 68 + k], T[(rq * 4 + 1) * 68 + k],
                                       T[(rq * 4 + 2) * 68 + k], T[(rq * 4 + 3) * 68 + k]);
                Bt4[(c * 64 + k) * 4 + rq] = g;
                unsigned int lo = (unsigned int)f2bf(g.x) | ((unsigned int)f2bf(g.y) << 16);
                unsigned int hi = (unsigned int)f2bf(g.z) | ((unsigned int)f2bf(g.w) << 16);
                *(uint2*)(Bt16p + (size_t)(c * 64 + k) * 16 + rq * 4) = make_uint2(lo, hi);
            }
            {
                int r = tid >> 4, ow = tid & 15;
                float4 g = make_float4(U[(ow * 4 + 0) * 20 + r], U[(ow * 4 + 1) * 20 + r],
                                       U[(ow * 4 + 2) * 20 + r], U[(ow * 4 + 3) * 20 + r]);
                At4[r * 256 + c * 16 + ow] = g;
            }
            __syncthreads();
        }
    } else {
        const int qb = blockIdx.x - 128;    // 0..3
        if (qb == 0) {
            if (tid < 64) counts[tid] = 0;
            if (tid == 64) flagcnt[0] = 0;
            {
                const int p = tid >> 3, seg = tid & 7;
                const float* a = proto + (size_t)p * KDIM + seg * 128;
                double s = 0.0;
                for (int k = 0; k < 128; ++k) {
                    double v = (double)a[k];
                    s = fma(v, v, s);
                }
                red[p][seg] = s;
            }
            __syncthreads();
            if (tid < 32) {
                double acc = red[tid][0];
                #pragma unroll
                for (int j = 1; j < 8; ++j) acc += red[tid][j];
                p2g[tid] = acc;
            }
        }
        float4* Pt4 = (float4*)Pt;
        for (int kc = qb * 8; kc < qb * 8 + 8; ++kc) {
            {
                int cc = tid >> 3, kk4 = tid & 7;
                float4 v = *(const float4*)(proto + (size_t)cc * KDIM + kc * 32 + kk4 * 4);
                TP[cc][kk4 * 4 + 0] = v.x; TP[cc][kk4 * 4 + 1] = v.y;
                TP[cc][kk4 * 4 + 2] = v.z; TP[cc][kk4 * 4 + 3] = v.w;
            }
            __syncthreads();
            {
                int kk = tid >> 3, c4 = tid & 7;
                float4 g = make_float4(TP[c4 * 4 + 0][kk], TP[c4 * 4 + 1][kk],
                                       TP[c4 * 4 + 2][kk], TP[c4 * 4 + 3][kk]);
                Pt4[(kc * 32 + kk) * 8 + c4] = g;
            }
            __syncthreads();
        }
    }
}

#define INS(kb, ib) { \
    bool lt1 = (kb) < k1, lt2 = (kb) < k2, lt3 = (kb) < k3, lt4 = (kb) < k4; \
    float nk4 = lt3 ? k3 : (lt4 ? (kb) : k4); int ni4 = lt3 ? i3 : (lt4 ? (ib) : i4); \
    float nk3 = lt2 ? k2 : (lt3 ? (kb) : k3); int ni3 = lt2 ? i2 : (lt3 ? (ib) : i3); \
    float nk2 = lt1 ? k1 : (lt2 ? (kb) : k2); int ni2 = lt1 ? i1 : (lt2 ? (ib) : i2); \
    k4 = nk4; i4 = ni4; k3 = nk3; i3 = ni3; k2 = nk2; i2 = ni2; \
    if (lt1) { k1 = (kb); i1 = (ib); } }

// ---------------------------------------------------------------------------
// Route v4 (round-27 best): 8 rows/block selection + fused h phase.
// ---------------------------------------------------------------------------
__global__ __launch_bounds__(256) void route_kernel(
    const float* __restrict__ x, const float* __restrict__ Pt,
    const float* __restrict__ temp, const double* __restrict__ p2g,
    const unsigned short* __restrict__ Bt16,
    float4* __restrict__ route, float* __restrict__ hws,
    int* __restrict__ counts, int* __restrict__ flagcnt,
    int* __restrict__ flaglist)
{
    __shared__ float Xs[8 * KDIM];
    __shared__ float part[4][8][33];
    __shared__ float x2p[4][8];
    __shared__ int lcnt[64];
    __shared__ int ps[16];

    const int tid = threadIdx.x;
    const int w = tid >> 6, l = tid & 63;
    const int c4 = l & 7, kslot8 = l >> 3;
    const int rowbase = blockIdx.x * 8;

    if (tid < 64) lcnt[tid] = 0;

    const float4* x4 = (const float4*)x;
    float sq[8];
    #pragma unroll
    for (int j = 0; j < 8; ++j) {
        float4 v = x4[(size_t)rowbase * 256 + j * 256 + tid];
        ((float4*)Xs)[j * 256 + tid] = v;
        sq[j] = fmaf(v.x, v.x, fmaf(v.y, v.y, fmaf(v.z, v.z, v.w * v.w)));
    }
    #pragma unroll
    for (int m = 1; m < 64; m <<= 1) {
        #pragma unroll
        for (int j = 0; j < 8; ++j) sq[j] += __shfl_xor(sq[j], m);
    }
    if (l == 0) {
        #pragma unroll
        for (int j = 0; j < 8; ++j) x2p[w][j] = sq[j];
    }
    __syncthreads();

    {
        float acc[8][4];
        #pragma unroll
        for (int j = 0; j < 8; ++j)
            #pragma unroll
            for (int jj = 0; jj < 4; ++jj) acc[j][jj] = 0.f;

        const float4* Pt4 = (const float4*)Pt;
        const int kbase = w * 256;
        #pragma unroll 4
        for (int i = 0; i < 32; ++i) {
            const int k = kbase + i * 8 + kslot8;
            float4 pv = Pt4[k * 8 + c4];
            #pragma unroll
            for (int j = 0; j < 8; ++j) {
                float xv = Xs[j * KDIM + k];
                acc[j][0] = fmaf(xv, pv.x, acc[j][0]);
                acc[j][1] = fmaf(xv, pv.y, acc[j][1]);
                acc[j][2] = fmaf(xv, pv.z, acc[j][2]);
                acc[j][3] = fmaf(xv, pv.w, acc[j][3]);
            }
        }
        #pragma unroll
        for (int m = 8; m < 64; m <<= 1) {
            #pragma unroll
            for (int j = 0; j < 8; ++j) {
                acc[j][0] += __shfl_xor(acc[j][0], m);
                acc[j][1] += __shfl_xor(acc[j][1], m);
                acc[j][2] += __shfl_xor(acc[j][2], m);
                acc[j][3] += __shfl_xor(acc[j][3], m);
            }
        }
        if (kslot8 == 0) {
            #pragma unroll
            for (int j = 0; j < 8; ++j) {
                part[w][j][4 * c4 + 0] = acc[j][0];
                part[w][j][4 * c4 + 1] = acc[j][1];
                part[w][j][4 * c4 + 2] = acc[j][2];
                part[w][j][4 * c4 + 3] = acc[j][3];
            }
        }
    }
    __syncthreads();

    {
        const int rowsel = tid >> 5, c = tid & 31;
        float dsum = (part[0][rowsel][c] + part[1][rowsel][c])
                   + (part[2][rowsel][c] + part[3][rowsel][c]);
        float key = (float)(p2g[c] - 2.0 * (double)dsum);
        float x2 = (x2p[0][rowsel] + x2p[1][rowsel])
                 + (x2p[2][rowsel] + x2p[3][rowsel]);

        float k1 = key, k2 = 3.0e38f, k3 = 3.1e38f, k4 = 3.2e38f;
        int i1 = c, i2 = 64, i3 = 65, i4 = 66;
        #pragma unroll
        for (int m = 1; m < 32; m <<= 1) {
            float b1 = __shfl_xor(k1, m), b2 = __shfl_xor(k2, m);
            float b3 = __shfl_xor(k3, m), b4 = __shfl_xor(k4, m);
            int j1 = __shfl_xor(i1, m), j2 = __shfl_xor(i2, m);
            int j3 = __shfl_xor(i3, m), j4 = __shfl_xor(i4, m);
            INS(b1, j1); INS(b2, j2); INS(b3, j3); INS(b4, j4);
        }
        if (c == 0) {
            const int row = rowbase + rowsel;
            const float tf = fmaxf(fabsf(temp[0]), 0.1f);
            bool amb = (k2 - k1 < DELTA) || (k3 - k2 < DELTA)
                    || (fabsf((k3 - k2) - (float)TIE_EPS) < DELTA)
                    || (k4 - k3 < DELTA);
            bool tie = (k3 - k2) < (float)TIE_EPS;
            bool take3 = tie && (i3 < i2);
            float ksel = take3 ? k3 : k2;
            int   isel = take3 ? i3 : i2;
            float d0 = sqrtf(fmaxf(x2 + k1, 0.f));
            float d1 = sqrtf(fmaxf(x2 + ksel, 0.f));
            float e = expf((d0 - d1) / tf);
            float w0 = 1.f / (1.f + e);
            route[row] = make_float4(__int_as_float(i1), __int_as_float(isel),
                                     w0, e * w0);
            ps[2 * rowsel + 0] = i1;
            ps[2 * rowsel + 1] = isel;
            atomicAdd(&lcnt[i1], 1);
            atomicAdd(&lcnt[32 + isel], 1);
            if (amb) {
                int fi = atomicAdd(flagcnt, 1);
                if (fi < FLAG_CAP) flaglist[fi] = row;
            }
        }
    }
    __syncthreads();
    if (tid < 64) atomicAdd(&counts[tid], lcnt[tid]);

    // ---- fused h phase (h v10 body; Xs already staged) ----
    {
        const int pair = tid >> 4;          // row*2 + slot
        const int kslot = (tid >> 2) & 3;
        const int r4 = tid & 3;
        const int rrow = pair >> 1, slot = pair & 1;
        const unsigned short* Bp = Bt16 + (size_t)ps[pair] * KDIM * RNK + r4 * 4;
        const float* Xr = &Xs[rrow * KDIM];

        float4 acc = {0.f, 0.f, 0.f, 0.f};
        #pragma unroll 8
        for (int i = 0; i < 256; ++i) {
            const int k = i * 4 + kslot;
            float xv = Xr[k];
            uint2 bv = *(const uint2*)(Bp + (size_t)k * 16);
            float b0 = __uint_as_float((bv.x & 0xFFFFu) << 16);
            float b1 = __uint_as_float(bv.x & 0xFFFF0000u);
            float b2 = __uint_as_float((bv.y & 0xFFFFu) << 16);
            float b3 = __uint_as_float(bv.y & 0xFFFF0000u);
            acc.x = fmaf(xv, b0, acc.x);
            acc.y = fmaf(xv, b1, acc.y);
            acc.z = fmaf(xv, b2, acc.z);
            acc.w = fmaf(xv, b3, acc.w);
        }
        #pragma unroll
        for (int msk = 4; msk < 16; msk <<= 1) {
            acc.x += __shfl_xor(acc.x, msk);
            acc.y += __shfl_xor(acc.y, msk);
            acc.z += __shfl_xor(acc.z, msk);
            acc.w += __shfl_xor(acc.w, msk);
        }
        if (kslot == 0)
            *(float4*)(hws + (size_t)(slot * ROWS_TOTAL + rowbase + rrow) * 16 + r4 * 4) = acc;
    }
}

// ---------------------------------------------------------------------------
// Refine + scan v2: exact f64 re-selection for flagged rows; recompute h for
// changed slot protos (bf16-B). Then scan counts -> segs. Single block.
// ---------------------------------------------------------------------------
__global__ __launch_bounds__(256) void refine_scan_kernel(
    const float* __restrict__ x, const float* __restrict__ proto,
    const float* __restrict__ temp, const double* __restrict__ p2g,
    const unsigned short* __restrict__ Bt16,
    float4* __restrict__ route, float* __restrict__ hws,
    int* __restrict__ counts, const int* __restrict__ flagcnt,
    const int* __restrict__ flaglist, int2* __restrict__ segs)
{
    const int tid = threadIdx.x;
    const int w = tid >> 6, l = tid & 63;
    const int c = l & 31, half = l >> 5;
    const int n = min(flagcnt[0], FLAG_CAP);

    for (int f = w; f < n; f += 4) {
        const int row = flaglist[f];
        const float* xr = x + (size_t)row * KDIM;
        double xs = 0.0;
        for (int k = l * 16; k < l * 16 + 16; ++k) {
            double v = (double)xr[k];
            xs = fma(v, v, xs);
        }
        #pragma unroll
        for (int m = 1; m < 64; m <<= 1) xs += __shfl_xor(xs, m);
        const float* pr = proto + (size_t)c * KDIM + half * 512;
        const float* xh = xr + half * 512;
        double d0a = 0.0, d1a = 0.0;
        for (int k = 0; k < 512; k += 2) {
            d0a = fma((double)xh[k], (double)pr[k], d0a);
            d1a = fma((double)xh[k + 1], (double)pr[k + 1], d1a);
        }
        double acc = d0a + d1a;
        acc += __shfl_xor(acc, 32);
        double key = p2g[c] - 2.0 * acc;

        double k1 = key, k2 = 1.0e300, k3 = 1.1e300;
        int i1 = c, i2 = 64, i3 = 65;
        #pragma unroll
        for (int m = 1; m < 32; m <<= 1) {
            double b1 = __shfl_xor(k1, m), b2 = __shfl_xor(k2, m), b3 = __shfl_xor(k3, m);
            int j1 = __shfl_xor(i1, m), j2 = __shfl_xor(i2, m), j3 = __shfl_xor(i3, m);
            bool c1 = (k1 < b1) || (k1 == b1 && i1 < j1);
            double m1 = c1 ? k1 : b1, M1 = c1 ? b1 : k1;
            int mi1 = c1 ? i1 : j1, Mi1 = c1 ? j1 : i1;
            bool c2 = (k2 < b2) || (k2 == b2 && i2 < j2);
            double m2 = c2 ? k2 : b2;
            int mi2 = c2 ? i2 : j2;
            bool c3 = (k3 < b3) || (k3 == b3 && i3 < j3);
            double m3 = c3 ? k3 : b3;
            int mi3 = c3 ? i3 : j3;
            bool c4 = (M1 < m2) || (M1 == m2 && Mi1 < mi2);
            double t2 = c4 ? M1 : m2, T2 = c4 ? m2 : M1;
            int ti2 = c4 ? Mi1 : mi2, Ti2 = c4 ? mi2 : Mi1;
            bool c5 = (T2 < m3) || (T2 == m3 && Ti2 < mi3);
            k1 = m1; i1 = mi1;
            k2 = t2; i2 = ti2;
            k3 = c5 ? T2 : m3; i3 = c5 ? Ti2 : mi3;
        }
        bool tie = (k3 - k2) < TIE_EPS;
        bool take3 = tie && (i3 < i2);
        int isel = take3 ? i3 : i2;
        double ksel = take3 ? k3 : k2;

        float4 old = route[row];
        int oi1 = __float_as_int(old.x), oisel = __float_as_int(old.y);

        if (l == 0) {
            const double tmp = (double)fmaxf(fabsf(temp[0]), 0.1f);
            double dd0 = sqrt(fmax(xs + k1, 0.0));
            double dd1 = sqrt(fmax(xs + ksel, 0.0));
            float e = expf((float)((dd0 - dd1) / tmp));
            float w0 = 1.f / (1.f + e);
            if (oi1 != i1) { atomicAdd(&counts[oi1], -1); atomicAdd(&counts[i1], 1); }
            if (oisel != isel) { atomicAdd(&counts[32 + oisel], -1); atomicAdd(&counts[32 + isel], 1); }
            route[row] = make_float4(__int_as_float(i1), __int_as_float(isel),
                                     w0, e * w0);
        }
        #pragma unroll
        for (int sl = 0; sl < 2; ++sl) {
            int np = sl ? isel : i1;
            int op = sl ? oisel : oi1;
            if (np != op) {
                const int r = l & 15, kq = l >> 4;
                const unsigned short* Bp = Bt16 + (size_t)np * KDIM * RNK + r;
                float hacc = 0.f;
                for (int k = kq * 256; k < kq * 256 + 256; ++k) {
                    unsigned int bu = (unsigned int)Bp[(size_t)k * 16] << 16;
                    hacc = fmaf(xr[k], __uint_as_float(bu), hacc);
                }
                hacc += __shfl_xor(hacc, 16);
                hacc += __shfl_xor(hacc, 32);
                if (kq == 0)
                    hws[(size_t)(sl * ROWS_TOTAL + row) * 16 + r] = hacc;
            }
        }
    }
    __syncthreads();
    if (tid < 64) {
        int v = atomicAdd(&counts[tid], 0);
        int sum = v;
        #pragma unroll
        for (int off = 1; off < 32; off <<= 1) {
            int u = __shfl_up(sum, off, 32);
            if ((tid & 31) >= off) sum += u;
        }
        counts[tid] = sum - v;
        segs[tid] = make_int2(sum - v, sum);
    }
}

__global__ __launch_bounds__(256) void scatter_kernel(
    const float4* __restrict__ route, int* __restrict__ counts,
    int* __restrict__ rowlist0, int* __restrict__ rowlist1)
{
    __shared__ int lcnt[64];
    __shared__ int gbase[64];
    const int tid = threadIdx.x;
    const int i = blockIdx.x * 256 + tid;
    if (tid < 64) lcnt[tid] = 0;
    __syncthreads();
    float4 rt = route[i];
    int p0 = __float_as_int(rt.x);
    int p1 = __float_as_int(rt.y);
    int lp0 = atomicAdd(&lcnt[p0], 1);
    int lp1 = atomicAdd(&lcnt[32 + p1], 1);
    __syncthreads();
    if (tid < 64) gbase[tid] = atomicAdd(&counts[tid], lcnt[tid]);
    __syncthreads();
    rowlist0[gbase[p0] + lp0] = i;
    rowlist1[gbase[32 + p1] + lp1] = i;
}

// ---------------------------------------------------------------------------
// y v4: row-indexed hws gather; At column in registers.
// ---------------------------------------------------------------------------
__global__ __launch_bounds__(256) void y_kernel(
    const float* __restrict__ At, const float* __restrict__ bias,
    const float4* __restrict__ route, const int* __restrict__ rowlist,
    const int2* __restrict__ segs, const float* __restrict__ hws,
    float* __restrict__ out, int slot)
{
    __shared__ float hsm[16][17];
    __shared__ int rows[16];
    __shared__ float wts[16];

    const int tid = threadIdx.x;
    const int f4 = tid;
    const int p = blockIdx.y;
    const int2 sg = segs[slot * 32 + p];
    const float4* Atp = (const float4*)(At + (size_t)p * RNK * OUTD);
    const float4 bb = ((const float4*)(bias + (size_t)p * OUTD))[f4];

    float4 Areg[16];
    #pragma unroll
    for (int r = 0; r < 16; ++r) Areg[r] = Atp[r * 256 + f4];

    for (int c = blockIdx.x; ; c += gridDim.x) {
        const int base = sg.x + c * 16;
        if (base >= sg.y) break;
        const int m = min(16, sg.y - base);

        if (tid < 16) {
            int rr = rowlist[base + min(tid, m - 1)];
            rows[tid] = rr;
            float4 rt = route[rr];
            wts[tid] = slot ? rt.w : rt.z;
        }
        __syncthreads();
        {
            const int e = tid >> 4, r = tid & 15;
            hsm[e][r] = hws[(size_t)(slot * ROWS_TOTAL + rows[e]) * 16 + r];
        }
        __syncthreads();

        for (int e = 0; e < m; ++e) {
            float4 acc = bb;
            #pragma unroll
            for (int r = 0; r < 16; ++r) {
                float hr = hsm[e][r];
                acc.x = fmaf(hr, Areg[r].x, acc.x);
                acc.y = fmaf(hr, Areg[r].y, acc.y);
                acc.z = fmaf(hr, Areg[r].z, acc.z);
                acc.w = fmaf(hr, Areg[r].w, acc.w);
            }
            const float w = wts[e];
            float4 v = make_float4(w * acc.x, w * acc.y, w * acc.z, w * acc.w);
            float4* dst = (float4*)(out + (size_t)rows[e] * OUTD) + f4;
            if (slot) {
                float4 old = *dst;
                v.x += old.x; v.y += old.y; v.z += old.z; v.w += old.w;
            }
            *dst = v;
        }
        __syncthreads();
    }
}

extern "C" void kernel_launch(void* const* d_in, const int* in_sizes, int n_in,
                              void* d_out, int out_size, void* d_ws, size_t ws_size,
                              hipStream_t stream) {
    const float* x     = (const float*)d_in[0];
    const float* proto = (const float*)d_in[1];
    const float* B     = (const float*)d_in[2];
    const float* A     = (const float*)d_in[3];
    const float* bias  = (const float*)d_in[4];
    const float* temp  = (const float*)d_in[5];
    float* out = (float*)d_out;

    char* wsb = (char*)d_ws;
    float4* route = (float4*)wsb;                              // 128 KB
    int* rowlist0 = (int*)(wsb + 131072);                      // 32 KB
    int* rowlist1 = rowlist0 + ROWS_TOTAL;                     // 32 KB
    int* counts   = (int*)(wsb + 196608);                      // 256 B
    int2* segs    = (int2*)(wsb + 196864);                     // 512 B
    double* p2g   = (double*)(wsb + 197376);                   // 256 B
    int* flagcnt  = (int*)(wsb + 197632);                      // 4 B
    int* flaglist = (int*)(wsb + 197760);                      // 16 KB
    float* Pt     = (float*)(wsb + 262144);                    // 128 KB
    float* Bt     = (float*)(wsb + 393216);                    // 2 MB
    float* At     = (float*)(wsb + 393216 + 2097152);          // 2 MB
    float* hws    = (float*)(wsb + 393216 + 2 * 2097152);      // 1 MB
    unsigned short* Bt16 = (unsigned short*)(wsb + 393216 + 3 * 2097152); // 1 MB

    prep_kernel<<<132, 256, 0, stream>>>(A, B, proto, At, Bt, Bt16, Pt, p2g,
                                         counts, flagcnt);
    route_kernel<<<ROWS_TOTAL / 8, 256, 0, stream>>>(x, Pt, temp, p2g, Bt16,
                                                     route, hws, counts,
                                                     flagcnt, flaglist);
    refine_scan_kernel<<<1, 256, 0, stream>>>(x, proto, temp, p2g, Bt16,
                                              route, hws, counts, flagcnt,
                                              flaglist, segs);
    scatter_kernel<<<ROWS_TOTAL / 256, 256, 0, stream>>>(route, counts, rowlist0, rowlist1);
    y_kernel<<<dim3(16, NPROTO), 256, 0, stream>>>(At, bias, route, rowlist0, segs, hws, out, 0);
    y_kernel<<<dim3(16, NPROTO), 256, 0, stream>>>(At, bias, route, rowlist1, segs, hws, out, 1);
}